// Round 5
// baseline (557.494 us; speedup 1.0000x reference)
//
#include <hip/hip_runtime.h>
#include <hip/hip_bf16.h>
#include <math.h>

#define B_   2048
#define N_   38
#define E_   4
#define DIN_ 9
#define H0_  256
#define H1_  256
#define L0_  512
#define M_   (B_ * N_)

typedef short bf16x8 __attribute__((ext_vector_type(8)));
typedef float f32x4 __attribute__((ext_vector_type(4)));

// ---------- bf16 helpers ----------
struct __align__(8) bf4 { __hip_bfloat16 x, y, z, w; };

__device__ __forceinline__ float b2f(unsigned short u) {
  return __uint_as_float((unsigned)u << 16);
}
__device__ __forceinline__ unsigned short f2b(float f) {
  __hip_bfloat16 h = __float2bfloat16(f);
  return *(unsigned short*)&h;
}
__device__ __forceinline__ float4 ld4v(const __hip_bfloat16* p) {
  bf4 v = *(const bf4*)p;
  return make_float4(__bfloat162float(v.x), __bfloat162float(v.y),
                     __bfloat162float(v.z), __bfloat162float(v.w));
}
__device__ __forceinline__ void st4v(__hip_bfloat16* p, float4 v) {
  bf4 o;
  o.x = __float2bfloat16(v.x); o.y = __float2bfloat16(v.y);
  o.z = __float2bfloat16(v.z); o.w = __float2bfloat16(v.w);
  *(bf4*)p = o;
}

static __device__ __forceinline__ float selc(const float4 v, int j) {
  return (j == 0) ? v.x : ((j == 1) ? v.y : ((j == 2) ? v.z : v.w));
}

__device__ __forceinline__ void fma_tile12(const float* __restrict__ zr, float4 w,
                                           float (&acc)[4][12]) {
#pragma unroll
  for (int l4 = 0; l4 < 3; ++l4) {
    float4 zv = *(const float4*)&zr[l4 * 4];
#pragma unroll
    for (int j = 0; j < 4; ++j) {
      float wj = selc(w, j);
      acc[j][l4 * 4 + 0] = fmaf(zv.x, wj, acc[j][l4 * 4 + 0]);
      acc[j][l4 * 4 + 1] = fmaf(zv.y, wj, acc[j][l4 * 4 + 1]);
      acc[j][l4 * 4 + 2] = fmaf(zv.z, wj, acc[j][l4 * 4 + 2]);
      acc[j][l4 * 4 + 3] = fmaf(zv.w, wj, acc[j][l4 * 4 + 3]);
    }
  }
}

__global__ void k_zero(float* __restrict__ p) { p[threadIdx.x] = 0.f; }

// wt0 fp32 [45][256]
__global__ void k_build_w0(const float* __restrict__ Ws, const float* __restrict__ We,
                           float* __restrict__ WT) {
  int i = blockIdx.x * 256 + threadIdx.x;
  if (i >= 45 * 256) return;
  int r = i / 256, c = i % 256;
  float v;
  if (r < 9) v = Ws[c * 9 + r];
  else { int rr = r - 9; int e = rr / 9, f = rr % 9; v = We[(c * 4 + e) * 9 + f]; }
  WT[i] = v;
}

// Wb1 bf16 [256 cols][1280 k]
__global__ void k_build_wb1(const float* __restrict__ Ws, const float* __restrict__ We,
                            unsigned short* __restrict__ WT) {
  int i = blockIdx.x * 256 + threadIdx.x;
  if (i >= 256 * 1280) return;
  int c = i / 1280, k = i % 1280;
  float v;
  if (k < 256) v = Ws[c * 256 + k];
  else { int kk = k - 256; int e = kk >> 8, f = kk & 255; v = We[(c * 4 + e) * 256 + f]; }
  WT[i] = f2b(v);
}

// Wl bf16 [512][256] = cast of lW0
__global__ void k_build_wl(const float* __restrict__ W, unsigned short* __restrict__ WT) {
  int i = blockIdx.x * 256 + threadIdx.x;
  if (i >= 512 * 256) return;
  WT[i] = f2b(W[i]);
}

// Wfb bf16 [32][512]: rows 0..17 = fW, rows 18..31 zero
__global__ void k_build_wf(const float* __restrict__ W, unsigned short* __restrict__ WT) {
  int i = blockIdx.x * 256 + threadIdx.x;
  if (i >= 32 * 512) return;
  int r = i / 512, k = i % 512;
  WT[i] = f2b(r < 18 ? W[r * 512 + k] : 0.f);
}

// ---------------- gconv layer 0 (K=45), fp32 VALU, output bf16 ----------------
__global__ __launch_bounds__(256) void k_gconv0(
    const float* __restrict__ adj, const float* __restrict__ x,
    const float* __restrict__ WT, const float* __restrict__ bs,
    const float* __restrict__ be, __hip_bfloat16* __restrict__ g) {
  __shared__ __align__(16) float adjF[E_ * N_ * N_];
  __shared__ __align__(16) float xc[45 * 48];
  __shared__ __align__(16) float arow[E_ * 48];
  const int b = blockIdx.x, tid = threadIdx.x;
  const size_t abase = (size_t)b * (E_ * N_ * N_);
  for (int i = tid; i < E_ * N_ * N_; i += 256) adjF[i] = adj[abase + i];
  for (int i = tid; i < N_ * DIN_; i += 256) {
    int n = i / DIN_;
    float v = x[(size_t)b * (N_ * DIN_) + i];
    xc[(i % DIN_) * 48 + n] = (n & 1) ? v : 0.f;   // MASK zeroes even rows
  }
  __syncthreads();
  for (int i = tid; i < E_ * N_; i += 256) {
    int e = i / N_, m = i % N_;
    const float* ar = &adjF[(e * N_ + m) * N_];
    float s = 0.f;
    for (int n = 0; n < N_; ++n) s += ar[n];
    arow[e * 48 + m] = s;
  }
  for (int i = tid; i < 36 * N_; i += 256) {
    int m = i % N_, ef = i / N_;
    int e = ef / 9, f = ef % 9;
    const float* ar = &adjF[(e * N_ + m) * N_];
    float s = 0.f;
    for (int n = 0; n < N_; ++n) s += ar[n] * xc[f * 48 + n];
    xc[(9 + ef) * 48 + m] = s;
  }
  __syncthreads();
  const int cg = tid & 63, mg = tid >> 6;
  const int c0 = cg * 4, mb = mg * 12;
  float acc[4][12];
#pragma unroll
  for (int j = 0; j < 4; ++j) {
    float bsv = bs[c0 + j];
    float b0 = be[(c0 + j) * 4 + 0], b1 = be[(c0 + j) * 4 + 1];
    float b2 = be[(c0 + j) * 4 + 2], b3 = be[(c0 + j) * 4 + 3];
#pragma unroll
    for (int l = 0; l < 12; ++l) {
      int m = mb + l;
      acc[j][l] = bsv + arow[0 * 48 + m] * b0 + arow[1 * 48 + m] * b1 +
                  arow[2 * 48 + m] * b2 + arow[3 * 48 + m] * b3;
    }
  }
  for (int k = 0; k < 45; ++k) {
    float4 w = *(const float4*)&WT[k * 256 + c0];
    fma_tile12(&xc[k * 48 + mb], w, acc);
  }
#pragma unroll
  for (int l = 0; l < 12; ++l) {
    int m = mb + l;
    if (m < N_) {
      float4 o; o.x = acc[0][l]; o.y = acc[1][l]; o.z = acc[2][l]; o.w = acc[3][l];
      st4v(&g[((size_t)b * N_ + m) * H0_ + c0], o);
    }
  }
}

// ---------------- BN stats (bf16 input): per-n sum/sumsq over (rows x C) ----------------
// grid (38, chunks); each y-chunk covers 64 "b" rows of the given buffer.
__global__ __launch_bounds__(256) void k_stats(const __hip_bfloat16* __restrict__ g, int C,
                                               float* __restrict__ st) {
  int n = blockIdx.x, s = blockIdx.y, tid = threadIdx.x;
  int C4 = C >> 2;
  float sum = 0.f, sq = 0.f;
  int per = 64 * C4;
  for (int j = tid; j < per; j += 256) {
    int bb = (s << 6) + j / C4, cc = j % C4;
    float4 v = ld4v(&g[((size_t)(bb * N_ + n) * C4 + cc) * 4]);
    sum += v.x + v.y + v.z + v.w;
    sq += v.x * v.x + v.y * v.y + v.z * v.z + v.w * v.w;
  }
  for (int off = 32; off; off >>= 1) {
    sum += __shfl_down(sum, off);
    sq += __shfl_down(sq, off);
  }
  __shared__ float rs[4], rq[4];
  int w = tid >> 6, l = tid & 63;
  if (!l) { rs[w] = sum; rq[w] = sq; }
  __syncthreads();
  if (!tid) {
    float S = 0.f, Q = 0.f;
    for (int i = 0; i < 4; ++i) { S += rs[i]; Q += rq[i]; }
    atomicAdd(&st[n * 2], S);
    atomicAdd(&st[n * 2 + 1], Q);
  }
}

// ---------------- fused layer 1: BN0+ReLU, z via MFMA, [h|z]*Wb1^T via MFMA ----------------
// One block per b, 512 threads (8 waves). A entirely LDS-resident; B streams from L2.
#define HBS 264   // hB row stride (shorts)
#define HTS 72    // hT row stride
#define ADS 72    // adjB row stride
#define ZBS 520   // zB row stride

template <int KC0, int KCN, int STRIDE>
__device__ __forceinline__ void gemm_seg(const unsigned short* __restrict__ Abase,
                                         const unsigned short* __restrict__ Wb1,
                                         int w, int lrow, int quad, f32x4 (&acc)[3][2]) {
#pragma unroll 8
  for (int kj = 0; kj < KCN; ++kj) {
    const int kc = KC0 + kj;
    const unsigned short* Ab = Abase + kj * 32;
    bf16x8 bb0 = *(const bf16x8*)&Wb1[(size_t)(w * 32 + lrow) * 1280 + kc * 32 + quad * 8];
    bf16x8 bb1 = *(const bf16x8*)&Wb1[(size_t)(w * 32 + 16 + lrow) * 1280 + kc * 32 + quad * 8];
#pragma unroll
    for (int mt = 0; mt < 3; ++mt) {
      bf16x8 aa = *(const bf16x8*)&Ab[(mt * 16 + lrow) * STRIDE + quad * 8];
      acc[mt][0] = __builtin_amdgcn_mfma_f32_16x16x32_bf16(aa, bb0, acc[mt][0], 0, 0, 0);
      acc[mt][1] = __builtin_amdgcn_mfma_f32_16x16x32_bf16(aa, bb1, acc[mt][1], 0, 0, 0);
    }
  }
}

__global__ __launch_bounds__(512) void k_gc1f(
    const float* __restrict__ adj, const unsigned short* __restrict__ g0,
    const unsigned short* __restrict__ Wb1, const float* __restrict__ bs,
    const float* __restrict__ be, const float* __restrict__ st,
    const float* __restrict__ gam, const float* __restrict__ bet,
    unsigned short* __restrict__ h2) {
  __shared__ __align__(16) unsigned short hB[48 * HBS];
  __shared__ __align__(16) unsigned short hT[256 * HTS];
  __shared__ __align__(16) unsigned short adjB[4 * 48 * ADS];
  __shared__ __align__(16) unsigned short zB[48 * ZBS];
  __shared__ float lbe[1024];
  __shared__ float lbias[256];
  __shared__ float arowS[4 * 48];
  __shared__ float aS[N_], bS[N_];
  const int b = blockIdx.x, tid = threadIdx.x;
  const uint4 z4 = make_uint4(0, 0, 0, 0);
  // ---- phase A: constants + zero-fills
  if (tid < N_) {
    const float cnt = 2048.f * 256.f;
    float mu = st[tid * 2] / cnt;
    float var = st[tid * 2 + 1] / cnt - mu * mu;
    float a = rsqrtf(var + 1e-5f) * gam[tid];
    aS[tid] = a;
    bS[tid] = bet[tid] - mu * a;
  }
  for (int i = tid; i < 1024; i += 512) lbe[i] = be[i];
  if (tid < 256) lbias[tid] = bs[tid];
  for (int i = tid; i < 330; i += 512) ((uint4*)hB)[38 * 33 + i] = z4;      // hB rows 38..47
  for (int i = tid; i < 256 * HTS / 8; i += 512) ((uint4*)hT)[i] = z4;     // hT all
  for (int i = tid; i < 4 * 48 * ADS / 8; i += 512) ((uint4*)adjB)[i] = z4; // adjB all
  __syncthreads();
  // ---- phase B: hB data (BN0+ReLU) + adjB data
  for (int i = tid; i < N_ * 32; i += 512) {
    int n = i >> 5, f8 = (i & 31) * 8;
    uint4 u = *(const uint4*)&g0[((size_t)b * N_ + n) * 256 + f8];
    float a = aS[n], bb = bS[n];
    float v[8];
    v[0] = b2f((unsigned short)(u.x & 0xffff)); v[1] = b2f((unsigned short)(u.x >> 16));
    v[2] = b2f((unsigned short)(u.y & 0xffff)); v[3] = b2f((unsigned short)(u.y >> 16));
    v[4] = b2f((unsigned short)(u.z & 0xffff)); v[5] = b2f((unsigned short)(u.z >> 16));
    v[6] = b2f((unsigned short)(u.w & 0xffff)); v[7] = b2f((unsigned short)(u.w >> 16));
#pragma unroll
    for (int j = 0; j < 8; ++j) v[j] = fmaxf(fmaf(v[j], a, bb), 0.f);
    uint4 o;
    o.x = (unsigned)f2b(v[0]) | ((unsigned)f2b(v[1]) << 16);
    o.y = (unsigned)f2b(v[2]) | ((unsigned)f2b(v[3]) << 16);
    o.z = (unsigned)f2b(v[4]) | ((unsigned)f2b(v[5]) << 16);
    o.w = (unsigned)f2b(v[6]) | ((unsigned)f2b(v[7]) << 16);
    *(uint4*)&hB[n * HBS + f8] = o;
  }
  for (int i = tid; i < E_ * N_ * N_; i += 512) {
    float v = adj[(size_t)b * (E_ * N_ * N_) + i];
    int e = i / (N_ * N_), r = i % (N_ * N_), m = r / N_, n = r % N_;
    adjB[(e * 48 + m) * ADS + n] = f2b(v);
  }
  __syncthreads();
  // ---- phase C: hT (transpose of hB) + arow
  for (int i = tid; i < 256 * 5; i += 512) {
    int f = i / 5, n0 = (i % 5) * 8;
    unsigned short t8[8];
#pragma unroll
    for (int j = 0; j < 8; ++j) {
      int n = n0 + j;
      t8[j] = (n < N_) ? hB[n * HBS + f] : (unsigned short)0;
    }
    uint4 o;
    o.x = (unsigned)t8[0] | ((unsigned)t8[1] << 16);
    o.y = (unsigned)t8[2] | ((unsigned)t8[3] << 16);
    o.z = (unsigned)t8[4] | ((unsigned)t8[5] << 16);
    o.w = (unsigned)t8[6] | ((unsigned)t8[7] << 16);
    *(uint4*)&hT[f * HTS + n0] = o;
  }
  if (tid < E_ * N_) {
    int e = tid / N_, m = tid % N_;
    float s = 0.f;
    for (int n = 0; n < N_; ++n) s += b2f(adjB[(e * 48 + m) * ADS + n]);
    arowS[e * 48 + m] = s;
  }
  __syncthreads();
  const int w = tid >> 6, L = tid & 63;
  const int lrow = L & 15, quad = L >> 4;
  f32x4 acc[3][2];
#pragma unroll
  for (int mt = 0; mt < 3; ++mt) {
    acc[mt][0] = (f32x4){0.f, 0.f, 0.f, 0.f};
    acc[mt][1] = (f32x4){0.f, 0.f, 0.f, 0.f};
  }
  // ---- z-GEMM for e-pair p: wave w handles e = p*2 + (w>>2), f-tiles (w&3)*4 .. +3
#pragma unroll 1
  for (int p = 0; p < 2; ++p) {
    {
      const int e = p * 2 + (w >> 2);
      const int ftb = (w & 3) * 4;
#pragma unroll
      for (int ftl = 0; ftl < 4; ++ftl) {
        const int ft = ftb + ftl;
        f32x4 za[3];
        za[0] = (f32x4){0.f, 0.f, 0.f, 0.f};
        za[1] = (f32x4){0.f, 0.f, 0.f, 0.f};
        za[2] = (f32x4){0.f, 0.f, 0.f, 0.f};
#pragma unroll
        for (int kk = 0; kk < 2; ++kk) {
          bf16x8 bh = *(const bf16x8*)&hT[(ft * 16 + lrow) * HTS + kk * 32 + quad * 8];
#pragma unroll
          for (int mt = 0; mt < 3; ++mt) {
            bf16x8 aa = *(const bf16x8*)&adjB[(e * 48 + mt * 16 + lrow) * ADS + kk * 32 + quad * 8];
            za[mt] = __builtin_amdgcn_mfma_f32_16x16x32_bf16(aa, bh, za[mt], 0, 0, 0);
          }
        }
#pragma unroll
        for (int mt = 0; mt < 3; ++mt)
#pragma unroll
          for (int reg = 0; reg < 4; ++reg)
            zB[(mt * 16 + quad * 4 + reg) * ZBS + (w >> 2) * 256 + ft * 16 + lrow] =
                f2b(za[mt][reg]);
      }
    }
    __syncthreads();
    // main GEMM segment
    if (p == 0) {
      gemm_seg<0, 8, HBS>(hB, Wb1, w, lrow, quad, acc);
      gemm_seg<8, 16, ZBS>(zB, Wb1, w, lrow, quad, acc);
    } else {
      gemm_seg<24, 16, ZBS>(zB, Wb1, w, lrow, quad, acc);
    }
    __syncthreads();
  }
  // ---- epilogue: bias + arow.be, store h2 rows
#pragma unroll
  for (int mt = 0; mt < 3; ++mt) {
#pragma unroll
    for (int reg = 0; reg < 4; ++reg) {
      const int m = mt * 16 + quad * 4 + reg;
      if (m < N_) {
        float a0 = arowS[0 * 48 + m], a1 = arowS[1 * 48 + m];
        float a2 = arowS[2 * 48 + m], a3 = arowS[3 * 48 + m];
#pragma unroll
        for (int nt = 0; nt < 2; ++nt) {
          const int col = w * 32 + nt * 16 + lrow;
          float4 bev = *(const float4*)&lbe[col * 4];
          float v = acc[mt][nt][reg] + lbias[col] +
                    a0 * bev.x + a1 * bev.y + a2 * bev.z + a3 * bev.w;
          h2[((size_t)b * N_ + m) * 256 + col] = f2b(v);
        }
      }
    }
  }
}

// ---------------- MFMA GEMM (lin0): C[local][Cstride] = A[m_base+..][K] * Bw^T + bias ----------------
__global__ __launch_bounds__(256) void k_mm(
    const unsigned short* __restrict__ A0, const unsigned short* __restrict__ Bw,
    const float* __restrict__ bias, unsigned short* __restrict__ Cout,
    int m_base, int kChunks, int sA0, int Cstride) {
  __shared__ __align__(16) unsigned short lA[64 * 32];
  __shared__ __align__(16) unsigned short lB[256 * 32];
  __shared__ float lbias[256];
  const int t = threadIdx.x;
  const int tileM = blockIdx.x, n_base = blockIdx.y * 256;
  const int K = kChunks * 32;
  for (int i = t; i < 256; i += 256) lbias[i] = bias[n_base + i];

  const int w = t >> 6, L = t & 63;
  const int lrow = L & 15, quad = L >> 4;
  const int srow = t >> 2, sseg = (t & 3) * 8;

  f32x4 acc[4][4];
#pragma unroll
  for (int mt = 0; mt < 4; ++mt)
#pragma unroll
    for (int nt = 0; nt < 4; ++nt) acc[mt][nt] = (f32x4){0.f, 0.f, 0.f, 0.f};

  for (int ki = 0; ki < kChunks; ++ki) {
    {
      const unsigned short* gp =
          A0 + (size_t)(m_base + tileM * 64 + srow) * sA0 + ki * 32 + sseg;
      __builtin_amdgcn_global_load_lds(
          (const __attribute__((address_space(1))) void*)gp,
          (__attribute__((address_space(3))) void*)(lA + w * 512), 16, 0, 0);
    }
#pragma unroll
    for (int r = 0; r < 4; ++r) {
      const unsigned short* gp = Bw + (size_t)(n_base + r * 64 + srow) * K + ki * 32 + sseg;
      __builtin_amdgcn_global_load_lds(
          (const __attribute__((address_space(1))) void*)gp,
          (__attribute__((address_space(3))) void*)(lB + r * 2048 + w * 512), 16, 0, 0);
    }
    __syncthreads();
    bf16x8 af[4], bfr[4];
#pragma unroll
    for (int mt = 0; mt < 4; ++mt)
      af[mt] = *(const bf16x8*)&lA[(mt * 16 + lrow) * 32 + quad * 8];
#pragma unroll
    for (int nt = 0; nt < 4; ++nt)
      bfr[nt] = *(const bf16x8*)&lB[(w * 64 + nt * 16 + lrow) * 32 + quad * 8];
#pragma unroll
    for (int mt = 0; mt < 4; ++mt)
#pragma unroll
      for (int nt = 0; nt < 4; ++nt)
        acc[mt][nt] = __builtin_amdgcn_mfma_f32_16x16x32_bf16(af[mt], bfr[nt], acc[mt][nt], 0, 0, 0);
    __syncthreads();
  }
#pragma unroll
  for (int mt = 0; mt < 4; ++mt) {
#pragma unroll
    for (int reg = 0; reg < 4; ++reg) {
      const size_t r_loc = (size_t)(tileM * 64 + mt * 16 + quad * 4 + reg);
#pragma unroll
      for (int nt = 0; nt < 4; ++nt) {
        const int col = w * 64 + nt * 16 + lrow;
        Cout[r_loc * Cstride + n_base + col] = f2b(acc[mt][nt][reg] + lbias[col]);
      }
    }
  }
}

// ---------------- prep2: BN1+ReLU elementwise in-place (bf16) ----------------
__global__ __launch_bounds__(256) void k_prep2(
    unsigned short* __restrict__ g, const float* __restrict__ st,
    const float* __restrict__ gam, const float* __restrict__ bet) {
  size_t i = (size_t)blockIdx.x * 256 + threadIdx.x;  // 8-elem groups
  int n = (int)((i >> 5) % N_);
  const float cnt = 2048.f * 256.f;
  float mu = st[n * 2] / cnt;
  float var = st[n * 2 + 1] / cnt - mu * mu;
  float a = rsqrtf(var + 1e-5f) * gam[n];
  float bb = bet[n] - mu * a;
  uint4 u = *((const uint4*)g + i);
  uint4 o;
  unsigned* up = (unsigned*)&u;
  unsigned* op = (unsigned*)&o;
#pragma unroll
  for (int j = 0; j < 4; ++j) {
    float lo = b2f((unsigned short)(up[j] & 0xffff));
    float hi = b2f((unsigned short)(up[j] >> 16));
    lo = fmaxf(fmaf(lo, a, bb), 0.f);
    hi = fmaxf(fmaf(hi, a, bb), 0.f);
    op[j] = (unsigned)f2b(lo) | ((unsigned)f2b(hi) << 16);
  }
  *((uint4*)g + i) = o;
}

// ---------------- final: MFMA 512->18 + coupling + logdet, BN2+ReLU fused ----------------
__global__ __launch_bounds__(256) void k_final(
    const unsigned short* __restrict__ g2, const float* __restrict__ x,
    const unsigned short* __restrict__ Wfb, const float* __restrict__ fb,
    const float* __restrict__ st, const float* __restrict__ gam,
    const float* __restrict__ bet, float* __restrict__ out, int b_off) {
  __shared__ __align__(16) unsigned short hA[48 * 520];  // bf16, row-pad 520
  __shared__ float lgS[48 * 20];
  __shared__ float aS[N_], bS[N_], fbS[20], red[4];
  const int b = b_off + blockIdx.x, tid = threadIdx.x;
  const int bl = blockIdx.x;  // local row index into g2 buffer
  if (tid < N_) {
    const float cnt = 2048.f * 512.f;
    float mu = st[tid * 2] / cnt;
    float var = st[tid * 2 + 1] / cnt - mu * mu;
    float a = rsqrtf(var + 1e-5f) * gam[tid];
    aS[tid] = a;
    bS[tid] = bet[tid] - mu * a;
  }
  if (tid >= 64 && tid < 82) fbS[tid - 64] = fb[tid - 64];
  __syncthreads();
  for (int i = tid; i < N_ * 64; i += 256) {
    int n = i >> 6, seg = (i & 63) * 8;
    uint4 u = *(const uint4*)&g2[((size_t)bl * N_ + n) * 512 + seg];
    float a = aS[n], bb = bS[n];
    float v[8];
    v[0] = b2f((unsigned short)(u.x & 0xffff)); v[1] = b2f((unsigned short)(u.x >> 16));
    v[2] = b2f((unsigned short)(u.y & 0xffff)); v[3] = b2f((unsigned short)(u.y >> 16));
    v[4] = b2f((unsigned short)(u.z & 0xffff)); v[5] = b2f((unsigned short)(u.z >> 16));
    v[6] = b2f((unsigned short)(u.w & 0xffff)); v[7] = b2f((unsigned short)(u.w >> 16));
#pragma unroll
    for (int j = 0; j < 8; ++j) v[j] = fmaxf(fmaf(v[j], a, bb), 0.f);
    uint4 o;
    o.x = (unsigned)f2b(v[0]) | ((unsigned)f2b(v[1]) << 16);
    o.y = (unsigned)f2b(v[2]) | ((unsigned)f2b(v[3]) << 16);
    o.z = (unsigned)f2b(v[4]) | ((unsigned)f2b(v[5]) << 16);
    o.w = (unsigned)f2b(v[6]) | ((unsigned)f2b(v[7]) << 16);
    *(uint4*)&hA[n * 520 + seg] = o;
  }
  for (int i = tid; i < 10 * 64; i += 256) {
    int n = 38 + (i >> 6), seg = (i & 63) * 8;
    *(uint4*)&hA[n * 520 + seg] = make_uint4(0, 0, 0, 0);
  }
  __syncthreads();
  const int w = tid >> 6, L = tid & 63;
  const int lrow = L & 15, quad = L >> 4;
  if (w < 3) {
    f32x4 acc0 = (f32x4){0.f, 0.f, 0.f, 0.f}, acc1 = (f32x4){0.f, 0.f, 0.f, 0.f};
#pragma unroll
    for (int ki = 0; ki < 16; ++ki) {
      bf16x8 af = *(const bf16x8*)&hA[(w * 16 + lrow) * 520 + ki * 32 + quad * 8];
      bf16x8 b0 = *(const bf16x8*)&Wfb[(size_t)lrow * 512 + ki * 32 + quad * 8];
      bf16x8 b1 = *(const bf16x8*)&Wfb[(size_t)(16 + lrow) * 512 + ki * 32 + quad * 8];
      acc0 = __builtin_amdgcn_mfma_f32_16x16x32_bf16(af, b0, acc0, 0, 0, 0);
      acc1 = __builtin_amdgcn_mfma_f32_16x16x32_bf16(af, b1, acc1, 0, 0, 0);
    }
#pragma unroll
    for (int reg = 0; reg < 4; ++reg) {
      int m = w * 16 + quad * 4 + reg;
      if (m < N_) {
        lgS[m * 20 + lrow] = acc0[reg] + fbS[lrow];
        if (lrow < 2) lgS[m * 20 + 16 + lrow] = acc1[reg] + fbS[16 + lrow];
      }
    }
  }
  __syncthreads();
  float ls = 0.f;
  for (int ii = tid; ii < 342; ii += 256) {
    int mm = ii / 9, d = ii % 9;
    float sl = lgS[mm * 20 + d];
    float tv = lgS[mm * 20 + 9 + d];
    float xv = x[((size_t)b * N_ + mm) * 9 + d];
    float sg = 1.f / (1.f + expf(-sl));
    float o = (mm & 1) ? xv : (xv + tv) * sg;
    out[((size_t)b * N_ + mm) * 9 + d] = o;
    ls += (sl >= 0.f) ? -log1pf(expf(-sl)) : (sl - log1pf(expf(sl)));
  }
#pragma unroll
  for (int off = 32; off; off >>= 1) ls += __shfl_down(ls, off);
  if (L == 0) red[w] = ls;
  __syncthreads();
  if (tid == 0) out[(size_t)B_ * 342 + b] = red[0] + red[1] + red[2] + red[3];
}

extern "C" void kernel_launch(void* const* d_in, const int* in_sizes, int n_in,
                              void* d_out, int out_size, void* d_ws, size_t ws_size,
                              hipStream_t stream) {
  (void)in_sizes; (void)n_in; (void)out_size;
  const float* adj  = (const float*)d_in[0];
  const float* x    = (const float*)d_in[1];
  const float* cWs0 = (const float*)d_in[2];
  const float* cbs0 = (const float*)d_in[3];
  const float* cWe0 = (const float*)d_in[4];
  const float* cbe0 = (const float*)d_in[5];
  const float* cg0  = (const float*)d_in[6];
  const float* cb0  = (const float*)d_in[7];
  const float* cWs1 = (const float*)d_in[8];
  const float* cbs1 = (const float*)d_in[9];
  const float* cWe1 = (const float*)d_in[10];
  const float* cbe1 = (const float*)d_in[11];
  const float* cg1  = (const float*)d_in[12];
  const float* cb1  = (const float*)d_in[13];
  const float* lW0  = (const float*)d_in[14];
  const float* lb0  = (const float*)d_in[15];
  const float* lg0  = (const float*)d_in[16];
  const float* lbb0 = (const float*)d_in[17];
  const float* fW   = (const float*)d_in[18];
  const float* fb   = (const float*)d_in[19];
  float* out = (float*)d_out;

  // ---- workspace layout (bytes) ----
  char* p = (char*)d_ws;
  float* stats = (float*)p;                     p += 1024;
  float* wt0   = (float*)p;                     p += 45 * 256 * 4;
  unsigned short* Wfb = (unsigned short*)p;     p += 32 * 512 * 2;
  unsigned short* Wb1 = (unsigned short*)p;     p += 256 * 1280 * 2;
  unsigned short* Wl  = (unsigned short*)p;     p += 512 * 256 * 2;
  unsigned short* buf1 = (unsigned short*)p;    p += (size_t)M_ * 256 * 2;   // g0
  unsigned short* buf3 = (unsigned short*)p;    p += (size_t)M_ * 256 * 2;   // h2
  unsigned short* g2 = (unsigned short*)p;      // full: M*512 ; fallback: (M/2)*512
  const size_t fixed = (size_t)((char*)g2 - (char*)d_ws);
  const bool full = ws_size >= fixed + (size_t)M_ * 512 * 2;

  k_zero<<<1, 256, 0, stream>>>(stats);
  k_build_w0<<<45, 256, 0, stream>>>(cWs0, cWe0, wt0);
  k_build_wb1<<<1280, 256, 0, stream>>>(cWs1, cWe1, Wb1);
  k_build_wl<<<512, 256, 0, stream>>>(lW0, Wl);
  k_build_wf<<<64, 256, 0, stream>>>(fW, Wfb);

  // layer 0
  k_gconv0<<<2048, 256, 0, stream>>>(adj, x, wt0, cbs0, cbe0, (__hip_bfloat16*)buf1);
  k_stats<<<dim3(38, 32), 256, 0, stream>>>((const __hip_bfloat16*)buf1, 256, stats);

  // layer 1: fully fused (BN0+ReLU, z via MFMA in LDS, big MFMA GEMM)
  k_gc1f<<<2048, 512, 0, stream>>>(adj, buf1, Wb1, cbs1, cbe1, stats, cg0, cb0, buf3);
  k_stats<<<dim3(38, 32), 256, 0, stream>>>((const __hip_bfloat16*)buf3, 256, stats + 76);

  // layer 2: BN1+relu in-place, then lin0 GEMM
  k_prep2<<<(M_ * 256 / 8 + 255) / 256, 256, 0, stream>>>(buf3, stats + 76, cg1, cb1);

  if (full) {
    k_mm<<<dim3(M_ / 64, 2), 256, 0, stream>>>(buf3, Wl, lb0, g2, 0, 8, 256, 512);
    k_stats<<<dim3(38, 32), 256, 0, stream>>>((const __hip_bfloat16*)g2, 512, stats + 152);
    k_final<<<2048, 256, 0, stream>>>(g2, x, Wfb, fb, stats + 152, lg0, lbb0, out, 0);
  } else {
    // half-buffer recompute path (g2 holds M/2 rows)
    for (int h = 0; h < 2; ++h) {
      k_mm<<<dim3(M_ / 128, 2), 256, 0, stream>>>(buf3, Wl, lb0, g2, h * (M_ / 2), 8, 256, 512);
      k_stats<<<dim3(38, 16), 256, 0, stream>>>((const __hip_bfloat16*)g2, 512, stats + 152);
    }
    for (int h = 0; h < 2; ++h) {
      k_mm<<<dim3(M_ / 128, 2), 256, 0, stream>>>(buf3, Wl, lb0, g2, h * (M_ / 2), 8, 256, 512);
      k_final<<<1024, 256, 0, stream>>>(g2, x, Wfb, fb, stats + 152, lg0, lbb0, out, h * 1024);
    }
  }
}

// Round 6
// 540.079 us; speedup vs baseline: 1.0322x; 1.0322x over previous
//
#include <hip/hip_runtime.h>
#include <hip/hip_bf16.h>
#include <math.h>

#define B_   2048
#define N_   38
#define E_   4
#define DIN_ 9
#define H0_  256
#define H1_  256
#define L0_  512
#define M_   (B_ * N_)

typedef short bf16x8 __attribute__((ext_vector_type(8)));
typedef float f32x4 __attribute__((ext_vector_type(4)));

// ---------- bf16 helpers ----------
struct __align__(8) bf4 { __hip_bfloat16 x, y, z, w; };

__device__ __forceinline__ float b2f(unsigned short u) {
  return __uint_as_float((unsigned)u << 16);
}
__device__ __forceinline__ unsigned short f2b(float f) {
  __hip_bfloat16 h = __float2bfloat16(f);
  return *(unsigned short*)&h;
}
__device__ __forceinline__ float4 ld4v(const __hip_bfloat16* p) {
  bf4 v = *(const bf4*)p;
  return make_float4(__bfloat162float(v.x), __bfloat162float(v.y),
                     __bfloat162float(v.z), __bfloat162float(v.w));
}
__device__ __forceinline__ void st4v(__hip_bfloat16* p, float4 v) {
  bf4 o;
  o.x = __float2bfloat16(v.x); o.y = __float2bfloat16(v.y);
  o.z = __float2bfloat16(v.z); o.w = __float2bfloat16(v.w);
  *(bf4*)p = o;
}

static __device__ __forceinline__ float selc(const float4 v, int j) {
  return (j == 0) ? v.x : ((j == 1) ? v.y : ((j == 2) ? v.z : v.w));
}

__device__ __forceinline__ void fma_tile12(const float* __restrict__ zr, float4 w,
                                           float (&acc)[4][12]) {
#pragma unroll
  for (int l4 = 0; l4 < 3; ++l4) {
    float4 zv = *(const float4*)&zr[l4 * 4];
#pragma unroll
    for (int j = 0; j < 4; ++j) {
      float wj = selc(w, j);
      acc[j][l4 * 4 + 0] = fmaf(zv.x, wj, acc[j][l4 * 4 + 0]);
      acc[j][l4 * 4 + 1] = fmaf(zv.y, wj, acc[j][l4 * 4 + 1]);
      acc[j][l4 * 4 + 2] = fmaf(zv.z, wj, acc[j][l4 * 4 + 2]);
      acc[j][l4 * 4 + 3] = fmaf(zv.w, wj, acc[j][l4 * 4 + 3]);
    }
  }
}

__global__ void k_zero(float* __restrict__ p) { p[threadIdx.x] = 0.f; }

// wt0 fp32 [45][256]
__global__ void k_build_w0(const float* __restrict__ Ws, const float* __restrict__ We,
                           float* __restrict__ WT) {
  int i = blockIdx.x * 256 + threadIdx.x;
  if (i >= 45 * 256) return;
  int r = i / 256, c = i % 256;
  float v;
  if (r < 9) v = Ws[c * 9 + r];
  else { int rr = r - 9; int e = rr / 9, f = rr % 9; v = We[(c * 4 + e) * 9 + f]; }
  WT[i] = v;
}

// Wb1 bf16 [256 cols][1280 k]
__global__ void k_build_wb1(const float* __restrict__ Ws, const float* __restrict__ We,
                            unsigned short* __restrict__ WT) {
  int i = blockIdx.x * 256 + threadIdx.x;
  if (i >= 256 * 1280) return;
  int c = i / 1280, k = i % 1280;
  float v;
  if (k < 256) v = Ws[c * 256 + k];
  else { int kk = k - 256; int e = kk >> 8, f = kk & 255; v = We[(c * 4 + e) * 256 + f]; }
  WT[i] = f2b(v);
}

// Wl bf16 [512][256] = cast of lW0
__global__ void k_build_wl(const float* __restrict__ W, unsigned short* __restrict__ WT) {
  int i = blockIdx.x * 256 + threadIdx.x;
  if (i >= 512 * 256) return;
  WT[i] = f2b(W[i]);
}

// Wfb bf16 [32][512]: rows 0..17 = fW, rows 18..31 zero
__global__ void k_build_wf(const float* __restrict__ W, unsigned short* __restrict__ WT) {
  int i = blockIdx.x * 256 + threadIdx.x;
  if (i >= 32 * 512) return;
  int r = i / 512, k = i % 512;
  WT[i] = f2b(r < 18 ? W[r * 512 + k] : 0.f);
}

// ---------------- gconv layer 0 (K=45), fp32 VALU, output bf16 ----------------
__global__ __launch_bounds__(256) void k_gconv0(
    const float* __restrict__ adj, const float* __restrict__ x,
    const float* __restrict__ WT, const float* __restrict__ bs,
    const float* __restrict__ be, __hip_bfloat16* __restrict__ g) {
  __shared__ __align__(16) float adjF[E_ * N_ * N_];
  __shared__ __align__(16) float xc[45 * 48];
  __shared__ __align__(16) float arow[E_ * 48];
  const int b = blockIdx.x, tid = threadIdx.x;
  const size_t abase = (size_t)b * (E_ * N_ * N_);
  for (int i = tid; i < E_ * N_ * N_; i += 256) adjF[i] = adj[abase + i];
  for (int i = tid; i < N_ * DIN_; i += 256) {
    int n = i / DIN_;
    float v = x[(size_t)b * (N_ * DIN_) + i];
    xc[(i % DIN_) * 48 + n] = (n & 1) ? v : 0.f;   // MASK zeroes even rows
  }
  __syncthreads();
  for (int i = tid; i < E_ * N_; i += 256) {
    int e = i / N_, m = i % N_;
    const float* ar = &adjF[(e * N_ + m) * N_];
    float s = 0.f;
    for (int n = 0; n < N_; ++n) s += ar[n];
    arow[e * 48 + m] = s;
  }
  for (int i = tid; i < 36 * N_; i += 256) {
    int m = i % N_, ef = i / N_;
    int e = ef / 9, f = ef % 9;
    const float* ar = &adjF[(e * N_ + m) * N_];
    float s = 0.f;
    for (int n = 0; n < N_; ++n) s += ar[n] * xc[f * 48 + n];
    xc[(9 + ef) * 48 + m] = s;
  }
  __syncthreads();
  const int cg = tid & 63, mg = tid >> 6;
  const int c0 = cg * 4, mb = mg * 12;
  float acc[4][12];
#pragma unroll
  for (int j = 0; j < 4; ++j) {
    float bsv = bs[c0 + j];
    float b0 = be[(c0 + j) * 4 + 0], b1 = be[(c0 + j) * 4 + 1];
    float b2 = be[(c0 + j) * 4 + 2], b3 = be[(c0 + j) * 4 + 3];
#pragma unroll
    for (int l = 0; l < 12; ++l) {
      int m = mb + l;
      acc[j][l] = bsv + arow[0 * 48 + m] * b0 + arow[1 * 48 + m] * b1 +
                  arow[2 * 48 + m] * b2 + arow[3 * 48 + m] * b3;
    }
  }
  for (int k = 0; k < 45; ++k) {
    float4 w = *(const float4*)&WT[k * 256 + c0];
    fma_tile12(&xc[k * 48 + mb], w, acc);
  }
#pragma unroll
  for (int l = 0; l < 12; ++l) {
    int m = mb + l;
    if (m < N_) {
      float4 o; o.x = acc[0][l]; o.y = acc[1][l]; o.z = acc[2][l]; o.w = acc[3][l];
      st4v(&g[((size_t)b * N_ + m) * H0_ + c0], o);
    }
  }
}

// ---------------- BN stats ----------------
__global__ __launch_bounds__(256) void k_stats(const __hip_bfloat16* __restrict__ g, int C,
                                               float* __restrict__ st) {
  int n = blockIdx.x, s = blockIdx.y, tid = threadIdx.x;
  int C4 = C >> 2;
  float sum = 0.f, sq = 0.f;
  int per = 64 * C4;
  for (int j = tid; j < per; j += 256) {
    int bb = (s << 6) + j / C4, cc = j % C4;
    float4 v = ld4v(&g[((size_t)(bb * N_ + n) * C4 + cc) * 4]);
    sum += v.x + v.y + v.z + v.w;
    sq += v.x * v.x + v.y * v.y + v.z * v.z + v.w * v.w;
  }
  for (int off = 32; off; off >>= 1) {
    sum += __shfl_down(sum, off);
    sq += __shfl_down(sq, off);
  }
  __shared__ float rs[4], rq[4];
  int w = tid >> 6, l = tid & 63;
  if (!l) { rs[w] = sum; rq[w] = sq; }
  __syncthreads();
  if (!tid) {
    float S = 0.f, Q = 0.f;
    for (int i = 0; i < 4; ++i) { S += rs[i]; Q += rq[i]; }
    atomicAdd(&st[n * 2], S);
    atomicAdd(&st[n * 2 + 1], Q);
  }
}

// ---------------- fused layer 1 v2: low-LDS (3 blocks/CU) ----------------
// Per b, 512 thr (8 waves). adjB(bf16, zero-padded cols) + zB(one e) in LDS;
// h fragments come straight from global g0 with BN+ReLU applied in-register.
#define ADJS 72   // adjB row stride (shorts)
#define ZBS2 264  // zB row stride (shorts)

__global__ __launch_bounds__(512, 4) void k_gc1f(
    const float* __restrict__ adj, const unsigned short* __restrict__ g0,
    const unsigned short* __restrict__ Wb1, const float* __restrict__ bs,
    const float* __restrict__ be, const float* __restrict__ st,
    const float* __restrict__ gam, const float* __restrict__ bet,
    unsigned short* __restrict__ h2) {
  __shared__ __align__(16) unsigned short adjB[4 * 38 * ADJS];  // 21888 B
  __shared__ __align__(16) unsigned short zB[48 * ZBS2];        // 25344 B
  __shared__ float arowS[4 * 48];
  __shared__ float aS[40], bS[40];
  __shared__ float lbias[256];
  const int b = blockIdx.x, tid = threadIdx.x;
  // phase 0: zero adjB (data + pads), BN coeffs, bias
  for (int i = tid; i < 4 * 38 * ADJS / 8; i += 512) ((uint4*)adjB)[i] = make_uint4(0, 0, 0, 0);
  if (tid < 40) {
    int n = tid < 38 ? tid : 37;
    const float cnt = 2048.f * 256.f;
    float mu = st[n * 2] / cnt;
    float var = st[n * 2 + 1] / cnt - mu * mu;
    float a = rsqrtf(var + 1e-5f) * gam[n];
    aS[tid] = a;
    bS[tid] = bet[n] - mu * a;
  }
  if (tid >= 64 && tid < 320) lbias[tid - 64] = bs[tid - 64];
  __syncthreads();
  // phase 1: adj -> adjB (bf16)
  for (int i = tid; i < 4 * 38 * 38; i += 512) {
    int em = i / 38, n = i % 38;
    adjB[em * ADJS + n] = f2b(adj[(size_t)b * 5776 + i]);
  }
  __syncthreads();
  // arow from adjB
  if (tid < 152) {
    int e = tid / 38, m = tid % 38;
    float s = 0.f;
    for (int n = 0; n < 38; ++n) s += b2f(adjB[(e * 38 + m) * ADJS + n]);
    arowS[e * 48 + m] = s;
  }
  const int w = tid >> 6, L = tid & 63;
  const int lrow = L & 15, quad = L >> 4;
  // z B-operand fragments (h^T): 4 frags per lane, global scalar loads + BN, kept in regs
  bf16x8 hfr[2][2];
#pragma unroll
  for (int ft = 0; ft < 2; ++ft) {
    const int fcol = (w * 2 + ft) * 16 + lrow;
#pragma unroll
    for (int kk = 0; kk < 2; ++kk) {
#pragma unroll
      for (int j = 0; j < 8; ++j) {
        int n = kk * 32 + quad * 8 + j;
        int nc = n < 38 ? n : 37;
        // n>=38 reads neighbor data; product is zeroed by adjB's zero k-columns
        float v = b2f(g0[((size_t)b * 38 + n) * 256 + fcol]);
        v = fmaxf(fmaf(v, aS[nc], bS[nc]), 0.f);
        hfr[ft][kk][j] = (short)f2b(v);
      }
    }
  }
  f32x4 acc[3][2];
#pragma unroll
  for (int mt = 0; mt < 3; ++mt) {
    acc[mt][0] = (f32x4){0.f, 0.f, 0.f, 0.f};
    acc[mt][1] = (f32x4){0.f, 0.f, 0.f, 0.f};
  }
#pragma unroll 1
  for (int e = 0; e < 4; ++e) {
    // ---- z-GEMM for this e (rows clamped; rows>=38 give junk, never stored)
    f32x4 za[3][2];
#pragma unroll
    for (int mt = 0; mt < 3; ++mt) {
      za[mt][0] = (f32x4){0.f, 0.f, 0.f, 0.f};
      za[mt][1] = (f32x4){0.f, 0.f, 0.f, 0.f};
    }
#pragma unroll
    for (int kk = 0; kk < 2; ++kk) {
#pragma unroll
      for (int mt = 0; mt < 3; ++mt) {
        int m = mt * 16 + lrow;
        int mc = m < 38 ? m : 37;
        bf16x8 aa = *(const bf16x8*)&adjB[(e * 38 + mc) * ADJS + kk * 32 + quad * 8];
        za[mt][0] = __builtin_amdgcn_mfma_f32_16x16x32_bf16(aa, hfr[0][kk], za[mt][0], 0, 0, 0);
        za[mt][1] = __builtin_amdgcn_mfma_f32_16x16x32_bf16(aa, hfr[1][kk], za[mt][1], 0, 0, 0);
      }
    }
    __syncthreads();  // prior main-seg finished reading zB
#pragma unroll
    for (int mt = 0; mt < 3; ++mt)
#pragma unroll
      for (int ft = 0; ft < 2; ++ft)
#pragma unroll
        for (int reg = 0; reg < 4; ++reg)
          zB[(mt * 16 + quad * 4 + reg) * ZBS2 + (w * 2 + ft) * 16 + lrow] =
              f2b(za[mt][ft][reg]);
    __syncthreads();
    // ---- main GEMM segments
    if (e == 0) {
      // h-part: k = 0..255, A from global g0 (BN+ReLU in reg)
#pragma unroll 2
      for (int kc = 0; kc < 8; ++kc) {
        bf16x8 bb0 = *(const bf16x8*)&Wb1[(size_t)(w * 32 + lrow) * 1280 + kc * 32 + quad * 8];
        bf16x8 bb1 = *(const bf16x8*)&Wb1[(size_t)(w * 32 + 16 + lrow) * 1280 + kc * 32 + quad * 8];
#pragma unroll
        for (int mt = 0; mt < 3; ++mt) {
          int m = mt * 16 + lrow;
          int mc = m < 38 ? m : 37;
          float a = aS[mc], bo = bS[mc];
          uint4 u = *(const uint4*)&g0[((size_t)b * 38 + mc) * 256 + kc * 32 + quad * 8];
          bf16x8 af;
          unsigned* up = (unsigned*)&u;
#pragma unroll
          for (int h = 0; h < 4; ++h) {
            float lo = fmaxf(fmaf(b2f((unsigned short)(up[h] & 0xffff)), a, bo), 0.f);
            float hi = fmaxf(fmaf(b2f((unsigned short)(up[h] >> 16)), a, bo), 0.f);
            af[h * 2] = (short)f2b(lo);
            af[h * 2 + 1] = (short)f2b(hi);
          }
          acc[mt][0] = __builtin_amdgcn_mfma_f32_16x16x32_bf16(af, bb0, acc[mt][0], 0, 0, 0);
          acc[mt][1] = __builtin_amdgcn_mfma_f32_16x16x32_bf16(af, bb1, acc[mt][1], 0, 0, 0);
        }
      }
    }
    // z-part: k = 256 + e*256 + kcl*32
#pragma unroll 2
    for (int kcl = 0; kcl < 8; ++kcl) {
      const int kbase = 256 + e * 256 + kcl * 32;
      bf16x8 bb0 = *(const bf16x8*)&Wb1[(size_t)(w * 32 + lrow) * 1280 + kbase + quad * 8];
      bf16x8 bb1 = *(const bf16x8*)&Wb1[(size_t)(w * 32 + 16 + lrow) * 1280 + kbase + quad * 8];
#pragma unroll
      for (int mt = 0; mt < 3; ++mt) {
        bf16x8 af = *(const bf16x8*)&zB[(mt * 16 + lrow) * ZBS2 + kcl * 32 + quad * 8];
        acc[mt][0] = __builtin_amdgcn_mfma_f32_16x16x32_bf16(af, bb0, acc[mt][0], 0, 0, 0);
        acc[mt][1] = __builtin_amdgcn_mfma_f32_16x16x32_bf16(af, bb1, acc[mt][1], 0, 0, 0);
      }
    }
  }
  // ---- epilogue: bias + arow.be
#pragma unroll
  for (int mt = 0; mt < 3; ++mt) {
#pragma unroll
    for (int reg = 0; reg < 4; ++reg) {
      const int m = mt * 16 + quad * 4 + reg;
      if (m < N_) {
        float a0 = arowS[0 * 48 + m], a1 = arowS[1 * 48 + m];
        float a2 = arowS[2 * 48 + m], a3 = arowS[3 * 48 + m];
#pragma unroll
        for (int nt = 0; nt < 2; ++nt) {
          const int col = w * 32 + nt * 16 + lrow;
          float4 bev = *(const float4*)&be[col * 4];
          float v = acc[mt][nt][reg] + lbias[col] +
                    a0 * bev.x + a1 * bev.y + a2 * bev.z + a3 * bev.w;
          h2[((size_t)b * N_ + m) * 256 + col] = f2b(v);
        }
      }
    }
  }
}

// ---------------- MFMA GEMM (lin0) ----------------
__global__ __launch_bounds__(256) void k_mm(
    const unsigned short* __restrict__ A0, const unsigned short* __restrict__ Bw,
    const float* __restrict__ bias, unsigned short* __restrict__ Cout,
    int m_base, int kChunks, int sA0, int Cstride) {
  __shared__ __align__(16) unsigned short lA[64 * 32];
  __shared__ __align__(16) unsigned short lB[256 * 32];
  __shared__ float lbias[256];
  const int t = threadIdx.x;
  const int tileM = blockIdx.x, n_base = blockIdx.y * 256;
  const int K = kChunks * 32;
  for (int i = t; i < 256; i += 256) lbias[i] = bias[n_base + i];

  const int w = t >> 6, L = t & 63;
  const int lrow = L & 15, quad = L >> 4;
  const int srow = t >> 2, sseg = (t & 3) * 8;

  f32x4 acc[4][4];
#pragma unroll
  for (int mt = 0; mt < 4; ++mt)
#pragma unroll
    for (int nt = 0; nt < 4; ++nt) acc[mt][nt] = (f32x4){0.f, 0.f, 0.f, 0.f};

  for (int ki = 0; ki < kChunks; ++ki) {
    {
      const unsigned short* gp =
          A0 + (size_t)(m_base + tileM * 64 + srow) * sA0 + ki * 32 + sseg;
      __builtin_amdgcn_global_load_lds(
          (const __attribute__((address_space(1))) void*)gp,
          (__attribute__((address_space(3))) void*)(lA + w * 512), 16, 0, 0);
    }
#pragma unroll
    for (int r = 0; r < 4; ++r) {
      const unsigned short* gp = Bw + (size_t)(n_base + r * 64 + srow) * K + ki * 32 + sseg;
      __builtin_amdgcn_global_load_lds(
          (const __attribute__((address_space(1))) void*)gp,
          (__attribute__((address_space(3))) void*)(lB + r * 2048 + w * 512), 16, 0, 0);
    }
    __syncthreads();
    bf16x8 af[4], bfr[4];
#pragma unroll
    for (int mt = 0; mt < 4; ++mt)
      af[mt] = *(const bf16x8*)&lA[(mt * 16 + lrow) * 32 + quad * 8];
#pragma unroll
    for (int nt = 0; nt < 4; ++nt)
      bfr[nt] = *(const bf16x8*)&lB[(w * 64 + nt * 16 + lrow) * 32 + quad * 8];
#pragma unroll
    for (int mt = 0; mt < 4; ++mt)
#pragma unroll
      for (int nt = 0; nt < 4; ++nt)
        acc[mt][nt] = __builtin_amdgcn_mfma_f32_16x16x32_bf16(af[mt], bfr[nt], acc[mt][nt], 0, 0, 0);
    __syncthreads();
  }
#pragma unroll
  for (int mt = 0; mt < 4; ++mt) {
#pragma unroll
    for (int reg = 0; reg < 4; ++reg) {
      const size_t r_loc = (size_t)(tileM * 64 + mt * 16 + quad * 4 + reg);
#pragma unroll
      for (int nt = 0; nt < 4; ++nt) {
        const int col = w * 64 + nt * 16 + lrow;
        Cout[r_loc * Cstride + n_base + col] = f2b(acc[mt][nt][reg] + lbias[col]);
      }
    }
  }
}

// ---------------- prep2: BN1+ReLU elementwise in-place (bf16) ----------------
__global__ __launch_bounds__(256) void k_prep2(
    unsigned short* __restrict__ g, const float* __restrict__ st,
    const float* __restrict__ gam, const float* __restrict__ bet) {
  size_t i = (size_t)blockIdx.x * 256 + threadIdx.x;
  int n = (int)((i >> 5) % N_);
  const float cnt = 2048.f * 256.f;
  float mu = st[n * 2] / cnt;
  float var = st[n * 2 + 1] / cnt - mu * mu;
  float a = rsqrtf(var + 1e-5f) * gam[n];
  float bb = bet[n] - mu * a;
  uint4 u = *((const uint4*)g + i);
  uint4 o;
  unsigned* up = (unsigned*)&u;
  unsigned* op = (unsigned*)&o;
#pragma unroll
  for (int j = 0; j < 4; ++j) {
    float lo = b2f((unsigned short)(up[j] & 0xffff));
    float hi = b2f((unsigned short)(up[j] >> 16));
    lo = fmaxf(fmaf(lo, a, bb), 0.f);
    hi = fmaxf(fmaf(hi, a, bb), 0.f);
    op[j] = (unsigned)f2b(lo) | ((unsigned)f2b(hi) << 16);
  }
  *((uint4*)g + i) = o;
}

// ---------------- final: MFMA 512->18 + coupling + logdet, BN2+ReLU fused ----------------
__global__ __launch_bounds__(256) void k_final(
    const unsigned short* __restrict__ g2, const float* __restrict__ x,
    const unsigned short* __restrict__ Wfb, const float* __restrict__ fb,
    const float* __restrict__ st, const float* __restrict__ gam,
    const float* __restrict__ bet, float* __restrict__ out, int b_off) {
  __shared__ __align__(16) unsigned short hA[48 * 520];
  __shared__ float lgS[48 * 20];
  __shared__ float aS[N_], bS[N_], fbS[20], red[4];
  const int b = b_off + blockIdx.x, tid = threadIdx.x;
  const int bl = blockIdx.x;
  if (tid < N_) {
    const float cnt = 2048.f * 512.f;
    float mu = st[tid * 2] / cnt;
    float var = st[tid * 2 + 1] / cnt - mu * mu;
    float a = rsqrtf(var + 1e-5f) * gam[tid];
    aS[tid] = a;
    bS[tid] = bet[tid] - mu * a;
  }
  if (tid >= 64 && tid < 82) fbS[tid - 64] = fb[tid - 64];
  __syncthreads();
  for (int i = tid; i < N_ * 64; i += 256) {
    int n = i >> 6, seg = (i & 63) * 8;
    uint4 u = *(const uint4*)&g2[((size_t)bl * N_ + n) * 512 + seg];
    float a = aS[n], bb = bS[n];
    float v[8];
    v[0] = b2f((unsigned short)(u.x & 0xffff)); v[1] = b2f((unsigned short)(u.x >> 16));
    v[2] = b2f((unsigned short)(u.y & 0xffff)); v[3] = b2f((unsigned short)(u.y >> 16));
    v[4] = b2f((unsigned short)(u.z & 0xffff)); v[5] = b2f((unsigned short)(u.z >> 16));
    v[6] = b2f((unsigned short)(u.w & 0xffff)); v[7] = b2f((unsigned short)(u.w >> 16));
#pragma unroll
    for (int j = 0; j < 8; ++j) v[j] = fmaxf(fmaf(v[j], a, bb), 0.f);
    uint4 o;
    o.x = (unsigned)f2b(v[0]) | ((unsigned)f2b(v[1]) << 16);
    o.y = (unsigned)f2b(v[2]) | ((unsigned)f2b(v[3]) << 16);
    o.z = (unsigned)f2b(v[4]) | ((unsigned)f2b(v[5]) << 16);
    o.w = (unsigned)f2b(v[6]) | ((unsigned)f2b(v[7]) << 16);
    *(uint4*)&hA[n * 520 + seg] = o;
  }
  for (int i = tid; i < 10 * 64; i += 256) {
    int n = 38 + (i >> 6), seg = (i & 63) * 8;
    *(uint4*)&hA[n * 520 + seg] = make_uint4(0, 0, 0, 0);
  }
  __syncthreads();
  const int w = tid >> 6, L = tid & 63;
  const int lrow = L & 15, quad = L >> 4;
  if (w < 3) {
    f32x4 acc0 = (f32x4){0.f, 0.f, 0.f, 0.f}, acc1 = (f32x4){0.f, 0.f, 0.f, 0.f};
#pragma unroll
    for (int ki = 0; ki < 16; ++ki) {
      bf16x8 af = *(const bf16x8*)&hA[(w * 16 + lrow) * 520 + ki * 32 + quad * 8];
      bf16x8 b0 = *(const bf16x8*)&Wfb[(size_t)lrow * 512 + ki * 32 + quad * 8];
      bf16x8 b1 = *(const bf16x8*)&Wfb[(size_t)(16 + lrow) * 512 + ki * 32 + quad * 8];
      acc0 = __builtin_amdgcn_mfma_f32_16x16x32_bf16(af, b0, acc0, 0, 0, 0);
      acc1 = __builtin_amdgcn_mfma_f32_16x16x32_bf16(af, b1, acc1, 0, 0, 0);
    }
#pragma unroll
    for (int reg = 0; reg < 4; ++reg) {
      int m = w * 16 + quad * 4 + reg;
      if (m < N_) {
        lgS[m * 20 + lrow] = acc0[reg] + fbS[lrow];
        if (lrow < 2) lgS[m * 20 + 16 + lrow] = acc1[reg] + fbS[16 + lrow];
      }
    }
  }
  __syncthreads();
  float ls = 0.f;
  for (int ii = tid; ii < 342; ii += 256) {
    int mm = ii / 9, d = ii % 9;
    float sl = lgS[mm * 20 + d];
    float tv = lgS[mm * 20 + 9 + d];
    float xv = x[((size_t)b * N_ + mm) * 9 + d];
    float sg = 1.f / (1.f + expf(-sl));
    float o = (mm & 1) ? xv : (xv + tv) * sg;
    out[((size_t)b * N_ + mm) * 9 + d] = o;
    ls += (sl >= 0.f) ? -log1pf(expf(-sl)) : (sl - log1pf(expf(sl)));
  }
#pragma unroll
  for (int off = 32; off; off >>= 1) ls += __shfl_down(ls, off);
  if (L == 0) red[w] = ls;
  __syncthreads();
  if (tid == 0) out[(size_t)B_ * 342 + b] = red[0] + red[1] + red[2] + red[3];
}

extern "C" void kernel_launch(void* const* d_in, const int* in_sizes, int n_in,
                              void* d_out, int out_size, void* d_ws, size_t ws_size,
                              hipStream_t stream) {
  (void)in_sizes; (void)n_in; (void)out_size;
  const float* adj  = (const float*)d_in[0];
  const float* x    = (const float*)d_in[1];
  const float* cWs0 = (const float*)d_in[2];
  const float* cbs0 = (const float*)d_in[3];
  const float* cWe0 = (const float*)d_in[4];
  const float* cbe0 = (const float*)d_in[5];
  const float* cg0  = (const float*)d_in[6];
  const float* cb0  = (const float*)d_in[7];
  const float* cWs1 = (const float*)d_in[8];
  const float* cbs1 = (const float*)d_in[9];
  const float* cWe1 = (const float*)d_in[10];
  const float* cbe1 = (const float*)d_in[11];
  const float* cg1  = (const float*)d_in[12];
  const float* cb1  = (const float*)d_in[13];
  const float* lW0  = (const float*)d_in[14];
  const float* lb0  = (const float*)d_in[15];
  const float* lg0  = (const float*)d_in[16];
  const float* lbb0 = (const float*)d_in[17];
  const float* fW   = (const float*)d_in[18];
  const float* fb   = (const float*)d_in[19];
  float* out = (float*)d_out;

  // ---- workspace layout (bytes) ----
  char* p = (char*)d_ws;
  float* stats = (float*)p;                     p += 1024;
  float* wt0   = (float*)p;                     p += 45 * 256 * 4;
  unsigned short* Wfb = (unsigned short*)p;     p += 32 * 512 * 2;
  unsigned short* Wb1 = (unsigned short*)p;     p += 256 * 1280 * 2;
  unsigned short* Wl  = (unsigned short*)p;     p += 512 * 256 * 2;
  unsigned short* buf1 = (unsigned short*)p;    p += (size_t)M_ * 256 * 2;   // g0
  unsigned short* buf3 = (unsigned short*)p;    p += (size_t)M_ * 256 * 2;   // h2
  unsigned short* g2 = (unsigned short*)p;      // full: M*512 ; fallback: (M/2)*512
  const size_t fixed = (size_t)((char*)g2 - (char*)d_ws);
  const bool full = ws_size >= fixed + (size_t)M_ * 512 * 2;

  k_zero<<<1, 256, 0, stream>>>(stats);
  k_build_w0<<<45, 256, 0, stream>>>(cWs0, cWe0, wt0);
  k_build_wb1<<<1280, 256, 0, stream>>>(cWs1, cWe1, Wb1);
  k_build_wl<<<512, 256, 0, stream>>>(lW0, Wl);
  k_build_wf<<<64, 256, 0, stream>>>(fW, Wfb);

  // layer 0
  k_gconv0<<<2048, 256, 0, stream>>>(adj, x, wt0, cbs0, cbe0, (__hip_bfloat16*)buf1);
  k_stats<<<dim3(38, 32), 256, 0, stream>>>((const __hip_bfloat16*)buf1, 256, stats);

  // layer 1: fused low-LDS version
  k_gc1f<<<2048, 512, 0, stream>>>(adj, buf1, Wb1, cbs1, cbe1, stats, cg0, cb0, buf3);
  k_stats<<<dim3(38, 32), 256, 0, stream>>>((const __hip_bfloat16*)buf3, 256, stats + 76);

  // layer 2: BN1+relu in-place, then lin0 GEMM
  k_prep2<<<(M_ * 256 / 8 + 255) / 256, 256, 0, stream>>>(buf3, stats + 76, cg1, cb1);

  if (full) {
    k_mm<<<dim3(M_ / 64, 2), 256, 0, stream>>>(buf3, Wl, lb0, g2, 0, 8, 256, 512);
    k_stats<<<dim3(38, 32), 256, 0, stream>>>((const __hip_bfloat16*)g2, 512, stats + 152);
    k_final<<<2048, 256, 0, stream>>>(g2, x, Wfb, fb, stats + 152, lg0, lbb0, out, 0);
  } else {
    for (int h = 0; h < 2; ++h) {
      k_mm<<<dim3(M_ / 128, 2), 256, 0, stream>>>(buf3, Wl, lb0, g2, h * (M_ / 2), 8, 256, 512);
      k_stats<<<dim3(38, 16), 256, 0, stream>>>((const __hip_bfloat16*)g2, 512, stats + 152);
    }
    for (int h = 0; h < 2; ++h) {
      k_mm<<<dim3(M_ / 128, 2), 256, 0, stream>>>(buf3, Wl, lb0, g2, h * (M_ / 2), 8, 256, 512);
      k_final<<<1024, 256, 0, stream>>>(g2, x, Wfb, fb, stats + 152, lg0, lbb0, out, h * 1024);
    }
  }
}

// Round 7
// 516.756 us; speedup vs baseline: 1.0788x; 1.0451x over previous
//
#include <hip/hip_runtime.h>
#include <hip/hip_bf16.h>
#include <math.h>

#define B_   2048
#define N_   38
#define E_   4
#define DIN_ 9
#define H0_  256
#define H1_  256
#define L0_  512
#define M_   (B_ * N_)

typedef short bf16x8 __attribute__((ext_vector_type(8)));
typedef float f32x4 __attribute__((ext_vector_type(4)));

// ---------- bf16 helpers ----------
struct __align__(8) bf4 { __hip_bfloat16 x, y, z, w; };

__device__ __forceinline__ float b2f(unsigned short u) {
  return __uint_as_float((unsigned)u << 16);
}
__device__ __forceinline__ unsigned short f2b(float f) {
  __hip_bfloat16 h = __float2bfloat16(f);
  return *(unsigned short*)&h;
}
__device__ __forceinline__ float4 ld4v(const __hip_bfloat16* p) {
  bf4 v = *(const bf4*)p;
  return make_float4(__bfloat162float(v.x), __bfloat162float(v.y),
                     __bfloat162float(v.z), __bfloat162float(v.w));
}
__device__ __forceinline__ void st4v(__hip_bfloat16* p, float4 v) {
  bf4 o;
  o.x = __float2bfloat16(v.x); o.y = __float2bfloat16(v.y);
  o.z = __float2bfloat16(v.z); o.w = __float2bfloat16(v.w);
  *(bf4*)p = o;
}

static __device__ __forceinline__ float selc(const float4 v, int j) {
  return (j == 0) ? v.x : ((j == 1) ? v.y : ((j == 2) ? v.z : v.w));
}

__device__ __forceinline__ void fma_tile12(const float* __restrict__ zr, float4 w,
                                           float (&acc)[4][12]) {
#pragma unroll
  for (int l4 = 0; l4 < 3; ++l4) {
    float4 zv = *(const float4*)&zr[l4 * 4];
#pragma unroll
    for (int j = 0; j < 4; ++j) {
      float wj = selc(w, j);
      acc[j][l4 * 4 + 0] = fmaf(zv.x, wj, acc[j][l4 * 4 + 0]);
      acc[j][l4 * 4 + 1] = fmaf(zv.y, wj, acc[j][l4 * 4 + 1]);
      acc[j][l4 * 4 + 2] = fmaf(zv.z, wj, acc[j][l4 * 4 + 2]);
      acc[j][l4 * 4 + 3] = fmaf(zv.w, wj, acc[j][l4 * 4 + 3]);
    }
  }
}

__global__ void k_zero(float* __restrict__ p) { p[threadIdx.x] = 0.f; }

// wt0 fp32 [45][256]
__global__ void k_build_w0(const float* __restrict__ Ws, const float* __restrict__ We,
                           float* __restrict__ WT) {
  int i = blockIdx.x * 256 + threadIdx.x;
  if (i >= 45 * 256) return;
  int r = i / 256, c = i % 256;
  float v;
  if (r < 9) v = Ws[c * 9 + r];
  else { int rr = r - 9; int e = rr / 9, f = rr % 9; v = We[(c * 4 + e) * 9 + f]; }
  WT[i] = v;
}

// Wbig bf16 [1280][256]: row j<256 -> cWs1[j][f]; row 256+e*256+c -> cWe1[(c*4+e)][f]
__global__ void k_build_wbig(const float* __restrict__ Ws, const float* __restrict__ We,
                             unsigned short* __restrict__ WT) {
  int i = blockIdx.x * 256 + threadIdx.x;
  if (i >= 1280 * 256) return;
  int j = i / 256, f = i % 256;
  float v;
  if (j < 256) v = Ws[j * 256 + f];
  else { int jj = j - 256; int e = jj >> 8, c = jj & 255; v = We[(c * 4 + e) * 256 + f]; }
  WT[i] = f2b(v);
}

// Wl bf16 [512][256] = cast of lW0
__global__ void k_build_wl(const float* __restrict__ W, unsigned short* __restrict__ WT) {
  int i = blockIdx.x * 256 + threadIdx.x;
  if (i >= 512 * 256) return;
  WT[i] = f2b(W[i]);
}

// Wfb bf16 [32][512]: rows 0..17 = fW, rows 18..31 zero
__global__ void k_build_wf(const float* __restrict__ W, unsigned short* __restrict__ WT) {
  int i = blockIdx.x * 256 + threadIdx.x;
  if (i >= 32 * 512) return;
  int r = i / 512, k = i % 512;
  WT[i] = f2b(r < 18 ? W[r * 512 + k] : 0.f);
}

// ---------------- gconv layer 0 (K=45), fp32 VALU, output bf16 ----------------
__global__ __launch_bounds__(256) void k_gconv0(
    const float* __restrict__ adj, const float* __restrict__ x,
    const float* __restrict__ WT, const float* __restrict__ bs,
    const float* __restrict__ be, __hip_bfloat16* __restrict__ g) {
  __shared__ __align__(16) float adjF[E_ * N_ * N_];
  __shared__ __align__(16) float xc[45 * 48];
  __shared__ __align__(16) float arow[E_ * 48];
  const int b = blockIdx.x, tid = threadIdx.x;
  const size_t abase = (size_t)b * (E_ * N_ * N_);
  for (int i = tid; i < E_ * N_ * N_; i += 256) adjF[i] = adj[abase + i];
  for (int i = tid; i < N_ * DIN_; i += 256) {
    int n = i / DIN_;
    float v = x[(size_t)b * (N_ * DIN_) + i];
    xc[(i % DIN_) * 48 + n] = (n & 1) ? v : 0.f;   // MASK zeroes even rows
  }
  __syncthreads();
  for (int i = tid; i < E_ * N_; i += 256) {
    int e = i / N_, m = i % N_;
    const float* ar = &adjF[(e * N_ + m) * N_];
    float s = 0.f;
    for (int n = 0; n < N_; ++n) s += ar[n];
    arow[e * 48 + m] = s;
  }
  for (int i = tid; i < 36 * N_; i += 256) {
    int m = i % N_, ef = i / N_;
    int e = ef / 9, f = ef % 9;
    const float* ar = &adjF[(e * N_ + m) * N_];
    float s = 0.f;
    for (int n = 0; n < N_; ++n) s += ar[n] * xc[f * 48 + n];
    xc[(9 + ef) * 48 + m] = s;
  }
  __syncthreads();
  const int cg = tid & 63, mg = tid >> 6;
  const int c0 = cg * 4, mb = mg * 12;
  float acc[4][12];
#pragma unroll
  for (int j = 0; j < 4; ++j) {
    float bsv = bs[c0 + j];
    float b0 = be[(c0 + j) * 4 + 0], b1 = be[(c0 + j) * 4 + 1];
    float b2 = be[(c0 + j) * 4 + 2], b3 = be[(c0 + j) * 4 + 3];
#pragma unroll
    for (int l = 0; l < 12; ++l) {
      int m = mb + l;
      acc[j][l] = bsv + arow[0 * 48 + m] * b0 + arow[1 * 48 + m] * b1 +
                  arow[2 * 48 + m] * b2 + arow[3 * 48 + m] * b3;
    }
  }
  for (int k = 0; k < 45; ++k) {
    float4 w = *(const float4*)&WT[k * 256 + c0];
    fma_tile12(&xc[k * 48 + mb], w, acc);
  }
#pragma unroll
  for (int l = 0; l < 12; ++l) {
    int m = mb + l;
    if (m < N_) {
      float4 o; o.x = acc[0][l]; o.y = acc[1][l]; o.z = acc[2][l]; o.w = acc[3][l];
      st4v(&g[((size_t)b * N_ + m) * H0_ + c0], o);
    }
  }
}

// ---------------- BN stats ----------------
__global__ __launch_bounds__(256) void k_stats(const __hip_bfloat16* __restrict__ g, int C,
                                               float* __restrict__ st) {
  int n = blockIdx.x, s = blockIdx.y, tid = threadIdx.x;
  int C4 = C >> 2;
  float sum = 0.f, sq = 0.f;
  int per = 64 * C4;
  for (int j = tid; j < per; j += 256) {
    int bb = (s << 6) + j / C4, cc = j % C4;
    float4 v = ld4v(&g[((size_t)(bb * N_ + n) * C4 + cc) * 4]);
    sum += v.x + v.y + v.z + v.w;
    sq += v.x * v.x + v.y * v.y + v.z * v.z + v.w * v.w;
  }
  for (int off = 32; off; off >>= 1) {
    sum += __shfl_down(sum, off);
    sq += __shfl_down(sq, off);
  }
  __shared__ float rs[4], rq[4];
  int w = tid >> 6, l = tid & 63;
  if (!l) { rs[w] = sum; rq[w] = sq; }
  __syncthreads();
  if (!tid) {
    float S = 0.f, Q = 0.f;
    for (int i = 0; i < 4; ++i) { S += rs[i]; Q += rq[i]; }
    atomicAdd(&st[n * 2], S);
    atomicAdd(&st[n * 2 + 1], Q);
  }
}

// ---------------- BN+ReLU elementwise in-place (bf16), rows of 256 cols ----------------
__global__ __launch_bounds__(256) void k_prep2(
    unsigned short* __restrict__ g, const float* __restrict__ st,
    const float* __restrict__ gam, const float* __restrict__ bet) {
  size_t i = (size_t)blockIdx.x * 256 + threadIdx.x;  // 8-elem groups
  int n = (int)((i >> 5) % N_);
  const float cnt = 2048.f * 256.f;
  float mu = st[n * 2] / cnt;
  float var = st[n * 2 + 1] / cnt - mu * mu;
  float a = rsqrtf(var + 1e-5f) * gam[n];
  float bb = bet[n] - mu * a;
  uint4 u = *((const uint4*)g + i);
  uint4 o;
  unsigned* up = (unsigned*)&u;
  unsigned* op = (unsigned*)&o;
#pragma unroll
  for (int j = 0; j < 4; ++j) {
    float lo = b2f((unsigned short)(up[j] & 0xffff));
    float hi = b2f((unsigned short)(up[j] >> 16));
    lo = fmaxf(fmaf(lo, a, bb), 0.f);
    hi = fmaxf(fmaf(hi, a, bb), 0.f);
    op[j] = (unsigned)f2b(lo) | ((unsigned)f2b(hi) << 16);
  }
  *((uint4*)g + i) = o;
}

// ---------------- k_gemm: 128x256-tile MFMA GEMM, K=256, A/B row stride = 256 ----------------
// C[row][Cstride] = A[row][0:256] * Bw[col][0:256]^T (+ bias[col]); 512 thr = 8 waves (2x4).
template <bool BIAS>
__global__ __launch_bounds__(512) void k_gemm(
    const unsigned short* __restrict__ A0, const unsigned short* __restrict__ Bw,
    const float* __restrict__ bias, unsigned short* __restrict__ Cout,
    int Cstride) {
  __shared__ __align__(16) unsigned short lA[128 * 32];
  __shared__ __align__(16) unsigned short lB[256 * 32];
  __shared__ float lbias[256];
  const int t = threadIdx.x;
  const int tileM = blockIdx.x, n_base = blockIdx.y * 256;
  if (BIAS && t < 256) lbias[t] = bias[n_base + t];
  const int w = t >> 6, L = t & 63;
  const int wr = w >> 2, wc = w & 3;
  const int lrow = L & 15, quad = L >> 4;
  const int srow = t >> 2, sseg = (t & 3) * 8;
  f32x4 acc[4][4];
#pragma unroll
  for (int mt = 0; mt < 4; ++mt)
#pragma unroll
    for (int nt = 0; nt < 4; ++nt) acc[mt][nt] = (f32x4){0.f, 0.f, 0.f, 0.f};

  for (int ki = 0; ki < 8; ++ki) {
    {
      const unsigned short* gp = A0 + (size_t)(tileM * 128 + srow) * 256 + ki * 32 + sseg;
      __builtin_amdgcn_global_load_lds(
          (const __attribute__((address_space(1))) void*)gp,
          (__attribute__((address_space(3))) void*)(lA + w * 512), 16, 0, 0);
    }
#pragma unroll
    for (int r = 0; r < 2; ++r) {
      const unsigned short* gp = Bw + (size_t)(n_base + r * 128 + srow) * 256 + ki * 32 + sseg;
      __builtin_amdgcn_global_load_lds(
          (const __attribute__((address_space(1))) void*)gp,
          (__attribute__((address_space(3))) void*)(lB + r * 4096 + w * 512), 16, 0, 0);
    }
    __syncthreads();
    bf16x8 af[4], bfr[4];
#pragma unroll
    for (int mt = 0; mt < 4; ++mt)
      af[mt] = *(const bf16x8*)&lA[(wr * 64 + mt * 16 + lrow) * 32 + quad * 8];
#pragma unroll
    for (int nt = 0; nt < 4; ++nt)
      bfr[nt] = *(const bf16x8*)&lB[(wc * 64 + nt * 16 + lrow) * 32 + quad * 8];
#pragma unroll
    for (int mt = 0; mt < 4; ++mt)
#pragma unroll
      for (int nt = 0; nt < 4; ++nt)
        acc[mt][nt] = __builtin_amdgcn_mfma_f32_16x16x32_bf16(af[mt], bfr[nt], acc[mt][nt], 0, 0, 0);
    __syncthreads();
  }
#pragma unroll
  for (int mt = 0; mt < 4; ++mt) {
#pragma unroll
    for (int reg = 0; reg < 4; ++reg) {
      const size_t row = (size_t)tileM * 128 + wr * 64 + mt * 16 + quad * 4 + reg;
#pragma unroll
      for (int nt = 0; nt < 4; ++nt) {
        const int lcol = wc * 64 + nt * 16 + lrow;
        float v = acc[mt][nt][reg];
        if (BIAS) v += lbias[lcol];
        Cout[row * Cstride + n_base + lcol] = f2b(v);
      }
    }
  }
}

// ---------------- k_hr: per-b contraction hr = adj_e x Y_e, + hs + bias + arow.be ----------------
// Y layout per local row (bl*38+n): [hs(256) | e0(256) | e1 | e2 | e3]. One block per b, 256 thr.
__global__ __launch_bounds__(256) void k_hr(
    const float* __restrict__ adj, const unsigned short* __restrict__ Y,
    const float* __restrict__ bs, const float* __restrict__ be,
    unsigned short* __restrict__ h2, int b_base) {
  __shared__ __align__(16) unsigned short adjE[4 * 48 * 64];  // [e][m(48)][n(64)] zero-padded
  __shared__ __align__(16) unsigned short Ybt[256 * 72];      // [c][n(64 used, pad 72)]
  __shared__ float arowS[4 * 48];
  const int t = threadIdx.x;
  const int bl = blockIdx.x, b = b_base + bl;
  for (int i = t; i < 4 * 48 * 64 / 8; i += 256) ((uint4*)adjE)[i] = make_uint4(0, 0, 0, 0);
#pragma unroll
  for (int n = 38; n < 64; ++n) Ybt[t * 72 + n] = 0;   // zero pad rows once (persist across e)
  __syncthreads();
  for (int i = t; i < 4 * 38 * 38; i += 256) {
    int e = i / 1444, r = i % 1444, m = r / 38, n = r % 38;
    adjE[(e * 48 + m) * 64 + n] = f2b(adj[(size_t)b * 5776 + i]);
  }
  __syncthreads();
  if (t < 152) {
    int e = t / 38, m = t % 38;
    float s = 0.f;
    for (int n = 0; n < 38; ++n) s += b2f(adjE[(e * 48 + m) * 64 + n]);
    arowS[e * 48 + m] = s;
  }
  const int w = t >> 6, L = t & 63;
  const int lrow = L & 15, quad = L >> 4;
  f32x4 acc[3][4];
#pragma unroll
  for (int mt = 0; mt < 3; ++mt)
#pragma unroll
    for (int nt = 0; nt < 4; ++nt) acc[mt][nt] = (f32x4){0.f, 0.f, 0.f, 0.f};
#pragma unroll 1
  for (int e = 0; e < 4; ++e) {
    __syncthreads();   // previous iteration's MFMA reads complete
    {
      // thread t = column c; coalesced across lanes for each n
      const unsigned short* yp = Y + (size_t)bl * 38 * 1280 + 256 + e * 256 + t;
#pragma unroll
      for (int n = 0; n < 38; ++n) Ybt[t * 72 + n] = yp[(size_t)n * 1280];
    }
    __syncthreads();
#pragma unroll
    for (int kk = 0; kk < 2; ++kk) {
      bf16x8 bb[4];
#pragma unroll
      for (int nt = 0; nt < 4; ++nt)
        bb[nt] = *(const bf16x8*)&Ybt[(w * 64 + nt * 16 + lrow) * 72 + kk * 32 + quad * 8];
#pragma unroll
      for (int mt = 0; mt < 3; ++mt) {
        bf16x8 aa = *(const bf16x8*)&adjE[(e * 48 + mt * 16 + lrow) * 64 + kk * 32 + quad * 8];
#pragma unroll
        for (int nt = 0; nt < 4; ++nt)
          acc[mt][nt] = __builtin_amdgcn_mfma_f32_16x16x32_bf16(aa, bb[nt], acc[mt][nt], 0, 0, 0);
      }
    }
  }
  // epilogue: + hs (Y cols 0..255) + bs + arow.be
#pragma unroll
  for (int mt = 0; mt < 3; ++mt) {
#pragma unroll
    for (int reg = 0; reg < 4; ++reg) {
      const int m = mt * 16 + quad * 4 + reg;
      if (m < N_) {
        float a0 = arowS[0 * 48 + m], a1 = arowS[1 * 48 + m];
        float a2 = arowS[2 * 48 + m], a3 = arowS[3 * 48 + m];
#pragma unroll
        for (int nt = 0; nt < 4; ++nt) {
          const int col = w * 64 + nt * 16 + lrow;
          float hs = b2f(Y[(size_t)(bl * 38 + m) * 1280 + col]);
          float4 bev = *(const float4*)&be[col * 4];
          float v = acc[mt][nt][reg] + hs + bs[col] +
                    a0 * bev.x + a1 * bev.y + a2 * bev.z + a3 * bev.w;
          h2[((size_t)b * N_ + m) * 256 + col] = f2b(v);
        }
      }
    }
  }
}

// ---------------- final: MFMA 512->18 + coupling + logdet, BN2+ReLU fused ----------------
__global__ __launch_bounds__(256) void k_final(
    const unsigned short* __restrict__ g2, const float* __restrict__ x,
    const unsigned short* __restrict__ Wfb, const float* __restrict__ fb,
    const float* __restrict__ st, const float* __restrict__ gam,
    const float* __restrict__ bet, float* __restrict__ out) {
  __shared__ __align__(16) unsigned short hA[48 * 520];
  __shared__ float lgS[48 * 20];
  __shared__ float aS[N_], bS[N_], fbS[20], red[4];
  const int b = blockIdx.x, tid = threadIdx.x;
  if (tid < N_) {
    const float cnt = 2048.f * 512.f;
    float mu = st[tid * 2] / cnt;
    float var = st[tid * 2 + 1] / cnt - mu * mu;
    float a = rsqrtf(var + 1e-5f) * gam[tid];
    aS[tid] = a;
    bS[tid] = bet[tid] - mu * a;
  }
  if (tid >= 64 && tid < 82) fbS[tid - 64] = fb[tid - 64];
  __syncthreads();
  for (int i = tid; i < N_ * 64; i += 256) {
    int n = i >> 6, seg = (i & 63) * 8;
    uint4 u = *(const uint4*)&g2[((size_t)b * N_ + n) * 512 + seg];
    float a = aS[n], bb = bS[n];
    float v[8];
    v[0] = b2f((unsigned short)(u.x & 0xffff)); v[1] = b2f((unsigned short)(u.x >> 16));
    v[2] = b2f((unsigned short)(u.y & 0xffff)); v[3] = b2f((unsigned short)(u.y >> 16));
    v[4] = b2f((unsigned short)(u.z & 0xffff)); v[5] = b2f((unsigned short)(u.z >> 16));
    v[6] = b2f((unsigned short)(u.w & 0xffff)); v[7] = b2f((unsigned short)(u.w >> 16));
#pragma unroll
    for (int j = 0; j < 8; ++j) v[j] = fmaxf(fmaf(v[j], a, bb), 0.f);
    uint4 o;
    o.x = (unsigned)f2b(v[0]) | ((unsigned)f2b(v[1]) << 16);
    o.y = (unsigned)f2b(v[2]) | ((unsigned)f2b(v[3]) << 16);
    o.z = (unsigned)f2b(v[4]) | ((unsigned)f2b(v[5]) << 16);
    o.w = (unsigned)f2b(v[6]) | ((unsigned)f2b(v[7]) << 16);
    *(uint4*)&hA[n * 520 + seg] = o;
  }
  for (int i = tid; i < 10 * 64; i += 256) {
    int n = 38 + (i >> 6), seg = (i & 63) * 8;
    *(uint4*)&hA[n * 520 + seg] = make_uint4(0, 0, 0, 0);
  }
  __syncthreads();
  const int w = tid >> 6, L = tid & 63;
  const int lrow = L & 15, quad = L >> 4;
  if (w < 3) {
    f32x4 acc0 = (f32x4){0.f, 0.f, 0.f, 0.f}, acc1 = (f32x4){0.f, 0.f, 0.f, 0.f};
#pragma unroll
    for (int ki = 0; ki < 16; ++ki) {
      bf16x8 af = *(const bf16x8*)&hA[(w * 16 + lrow) * 520 + ki * 32 + quad * 8];
      bf16x8 b0 = *(const bf16x8*)&Wfb[(size_t)lrow * 512 + ki * 32 + quad * 8];
      bf16x8 b1 = *(const bf16x8*)&Wfb[(size_t)(16 + lrow) * 512 + ki * 32 + quad * 8];
      acc0 = __builtin_amdgcn_mfma_f32_16x16x32_bf16(af, b0, acc0, 0, 0, 0);
      acc1 = __builtin_amdgcn_mfma_f32_16x16x32_bf16(af, b1, acc1, 0, 0, 0);
    }
#pragma unroll
    for (int reg = 0; reg < 4; ++reg) {
      int m = w * 16 + quad * 4 + reg;
      if (m < N_) {
        lgS[m * 20 + lrow] = acc0[reg] + fbS[lrow];
        if (lrow < 2) lgS[m * 20 + 16 + lrow] = acc1[reg] + fbS[16 + lrow];
      }
    }
  }
  __syncthreads();
  float ls = 0.f;
  for (int ii = tid; ii < 342; ii += 256) {
    int mm = ii / 9, d = ii % 9;
    float sl = lgS[mm * 20 + d];
    float tv = lgS[mm * 20 + 9 + d];
    float xv = x[((size_t)b * N_ + mm) * 9 + d];
    float sg = 1.f / (1.f + expf(-sl));
    float o = (mm & 1) ? xv : (xv + tv) * sg;
    out[((size_t)b * N_ + mm) * 9 + d] = o;
    ls += (sl >= 0.f) ? -log1pf(expf(-sl)) : (sl - log1pf(expf(sl)));
  }
#pragma unroll
  for (int off = 32; off; off >>= 1) ls += __shfl_down(ls, off);
  if (L == 0) red[w] = ls;
  __syncthreads();
  if (tid == 0) out[(size_t)B_ * 342 + b] = red[0] + red[1] + red[2] + red[3];
}

extern "C" void kernel_launch(void* const* d_in, const int* in_sizes, int n_in,
                              void* d_out, int out_size, void* d_ws, size_t ws_size,
                              hipStream_t stream) {
  (void)in_sizes; (void)n_in; (void)out_size; (void)ws_size;
  const float* adj  = (const float*)d_in[0];
  const float* x    = (const float*)d_in[1];
  const float* cWs0 = (const float*)d_in[2];
  const float* cbs0 = (const float*)d_in[3];
  const float* cWe0 = (const float*)d_in[4];
  const float* cbe0 = (const float*)d_in[5];
  const float* cg0  = (const float*)d_in[6];
  const float* cb0  = (const float*)d_in[7];
  const float* cWs1 = (const float*)d_in[8];
  const float* cbs1 = (const float*)d_in[9];
  const float* cWe1 = (const float*)d_in[10];
  const float* cbe1 = (const float*)d_in[11];
  const float* cg1  = (const float*)d_in[12];
  const float* cb1  = (const float*)d_in[13];
  const float* lW0  = (const float*)d_in[14];
  const float* lb0  = (const float*)d_in[15];
  const float* lg0  = (const float*)d_in[16];
  const float* lbb0 = (const float*)d_in[17];
  const float* fW   = (const float*)d_in[18];
  const float* fb   = (const float*)d_in[19];
  float* out = (float*)d_out;

  // ---- workspace layout (bytes): ~180 MB total ----
  char* p = (char*)d_ws;
  float* stats = (float*)p;                     p += 1024;
  float* wt0   = (float*)p;                     p += 45 * 256 * 4;
  unsigned short* Wfb  = (unsigned short*)p;    p += 32 * 512 * 2;
  unsigned short* Wbig = (unsigned short*)p;    p += 1280 * 256 * 2;
  unsigned short* Wl   = (unsigned short*)p;    p += 512 * 256 * 2;
  unsigned short* g0   = (unsigned short*)p;    p += (size_t)M_ * 256 * 2;
  unsigned short* h2   = (unsigned short*)p;    p += (size_t)M_ * 256 * 2;
  unsigned short* big  = (unsigned short*)p;    // max(Y-half 99.6MB, g2 79.7MB)
  unsigned short* Ybuf = big;                   // (M/2) x 1280
  unsigned short* g2   = big;                   // M x 512 (after Ybuf fully consumed)

  k_zero<<<1, 256, 0, stream>>>(stats);
  k_build_w0<<<45, 256, 0, stream>>>(cWs0, cWe0, wt0);
  k_build_wbig<<<1280, 256, 0, stream>>>(cWs1, cWe1, Wbig);
  k_build_wl<<<512, 256, 0, stream>>>(lW0, Wl);
  k_build_wf<<<64, 256, 0, stream>>>(fW, Wfb);

  // layer 0
  k_gconv0<<<2048, 256, 0, stream>>>(adj, x, wt0, cbs0, cbe0, (__hip_bfloat16*)g0);
  k_stats<<<dim3(38, 32), 256, 0, stream>>>((const __hip_bfloat16*)g0, 256, stats);
  k_prep2<<<M_ * 256 / 8 / 256, 256, 0, stream>>>(g0, stats, cg0, cb0);  // g0 := h

  // layer 1: Y = h * Wbig^T (GEMM), then per-b adj contraction; 2 halves
  for (int hh = 0; hh < 2; ++hh) {
    k_gemm<false><<<dim3(304, 5), 512, 0, stream>>>(
        g0 + (size_t)hh * (M_ / 2) * 256, Wbig, (const float*)nullptr, Ybuf, 1280);
    k_hr<<<1024, 256, 0, stream>>>(adj, Ybuf, cbs1, cbe1, h2, hh * 1024);
  }
  k_stats<<<dim3(38, 32), 256, 0, stream>>>((const __hip_bfloat16*)h2, 256, stats + 76);
  k_prep2<<<M_ * 256 / 8 / 256, 256, 0, stream>>>(h2, stats + 76, cg1, cb1);  // h2 := relu(bn)

  // layer 2: lin0 GEMM
  k_gemm<true><<<dim3(608, 2), 512, 0, stream>>>(h2, Wl, lb0, g2, 512);
  k_stats<<<dim3(38, 32), 256, 0, stream>>>((const __hip_bfloat16*)g2, 512, stats + 152);

  // final
  k_final<<<2048, 256, 0, stream>>>(g2, x, Wfb, fb, stats + 152, lg0, lbb0, out);
}